// Round 9
// baseline (380.836 us; speedup 1.0000x reference)
//
#include <hip/hip_runtime.h>
#include <hip/hip_bf16.h>

// HAN forward, del-branch only (add-branch _group output is unused in the reference).
// Inputs f32 / int32; output f32 [4096,256]. h and out_* stored bf16.
//
// R9 change (R8 dbuf was neutral: gate is memory-level parallelism, not barriers):
//  - gemm_h2: BM=128 BN=64, 1256 blocks (4.9/CU, LDS 30.7 KB), 2-DEEP register
//    prefetch (tiles k+1,k+2 in flight during compute) -> ~2x outstanding bytes.
//  - coalesced epilogue via LDS: acc -> LDS bf16 -> full-128B-line dwordx4 stores
//    (was 32B partial-line u16 scatter: WRITE 37 MB vs 20.5 ideal).

typedef unsigned short u16;
typedef __attribute__((ext_vector_type(8))) __bf16 bf16x8;
typedef __attribute__((ext_vector_type(4))) float f32x4;

__device__ inline float bf2f(u16 u) {
    union { unsigned int i; float f; } c; c.i = ((unsigned int)u) << 16; return c.f;
}
__device__ inline u16 f2bf(float f) {  // round-to-nearest-even
    union { float f; unsigned int i; } c; c.f = f;
    return (u16)((c.i + 0x7fffu + ((c.i >> 16) & 1u)) >> 16);
}
__device__ inline bf16x8 cvt8(f32x4 a, f32x4 b) {
    bf16x8 r;
    r[0] = (__bf16)a[0]; r[1] = (__bf16)a[1]; r[2] = (__bf16)a[2]; r[3] = (__bf16)a[3];
    r[4] = (__bf16)b[0]; r[5] = (__bf16)b[1]; r[6] = (__bf16)b[2]; r[7] = (__bf16)b[3];
    return r;
}
__device__ inline float fast_tanh(float x) {
    x = fminf(9.f, fmaxf(-9.f, x));
    float t = __expf(2.f * x);
    return (t - 1.f) / (t + 1.f);
}

// ---------------- 1. h = X @ W^T + b, both node types, BM=128 BN=64 -----------------
// 4 waves 2x2: wave = 64 rows x 32 cols = 4x2 frags = 8 MFMA/kstep.
// 2-deep reg prefetch + LDS double buffer; coalesced LDS epilogue.
#define SA 40
#define SE 72
__global__ __launch_bounds__(256) void gemm_h2(const float* __restrict__ X0, const float* __restrict__ W0,
                                               const float* __restrict__ b0, u16* __restrict__ H0,
                                               const float* __restrict__ X1, const float* __restrict__ W1,
                                               const float* __restrict__ b1, u16* __restrict__ H1, int M) {
    __shared__ u16 As[2][128 * SA];      // 20.0 KB
    __shared__ u16 Bs[2][64 * SA];       // 10.0 KB
    int id = blockIdx.x;
    int which = id >= 628;
    if (which) id -= 628;
    int bm = id >> 2, bn = id & 3;
    const float* X = which ? X1 : X0;
    const float* W = which ? W1 : W0;
    const float* bias = which ? b1 : b0;
    u16* H = which ? H1 : H0;

    int tid = threadIdx.x;
    int w = tid >> 6, lane = tid & 63;
    int wm = w & 1, wn = w >> 1;
    int row16 = lane & 15, quad = lane >> 4;

    // staging: thread -> A rows r0,r1 (chunk cc) + B row r0
    int r0 = tid >> 2, r1 = r0 + 64, cc = (tid & 3) * 8;
    int ar0 = bm * 128 + r0; if (ar0 > M - 1) ar0 = M - 1;
    int ar1 = bm * 128 + r1; if (ar1 > M - 1) ar1 = M - 1;
    const float* ag0 = X + (size_t)ar0 * 768 + cc;
    const float* ag1 = X + (size_t)ar1 * 768 + cc;
    const float* bg  = W + (size_t)(bn * 64 + r0) * 768 + cc;
    int off0 = r0 * SA + cc, off1 = r1 * SA + cc;

    int ardo = (wm * 64 + row16) * SA + quad * 8;
    int brdo = (wn * 32 + row16) * SA + quad * 8;

    f32x4 R[2][6];
#define LOADT(s, k)  { R[s][0] = *(const f32x4*)(ag0 + (k));     R[s][1] = *(const f32x4*)(ag0 + (k) + 4); \
                       R[s][2] = *(const f32x4*)(ag1 + (k));     R[s][3] = *(const f32x4*)(ag1 + (k) + 4); \
                       R[s][4] = *(const f32x4*)(bg  + (k));     R[s][5] = *(const f32x4*)(bg  + (k) + 4); }
#define WRITET(buf, s) { *(bf16x8*)(As[buf] + off0) = cvt8(R[s][0], R[s][1]); \
                         *(bf16x8*)(As[buf] + off1) = cvt8(R[s][2], R[s][3]); \
                         *(bf16x8*)(Bs[buf] + off0) = cvt8(R[s][4], R[s][5]); }

    LOADT(0, 0)
    LOADT(1, 32)
    WRITET(0, 0)
    __syncthreads();

    f32x4 acc[4][2] = {};
#pragma unroll
    for (int ks = 0; ks < 24; ++ks) {
        int cur = ks & 1;
        if (ks < 22) LOADT(cur, (ks + 2) * 32)      // 2-deep prefetch
        bf16x8 af[4], bv[2];
#pragma unroll
        for (int i = 0; i < 4; ++i) af[i] = *(const bf16x8*)(As[cur] + ardo + i * 16 * SA);
#pragma unroll
        for (int i = 0; i < 2; ++i) bv[i] = *(const bf16x8*)(Bs[cur] + brdo + i * 16 * SA);
#pragma unroll
        for (int mi = 0; mi < 4; ++mi)
#pragma unroll
            for (int ni = 0; ni < 2; ++ni)
                acc[mi][ni] = __builtin_amdgcn_mfma_f32_16x16x32_bf16(af[mi], bv[ni], acc[mi][ni], 0, 0, 0);
        if (ks < 23) {
            WRITET(cur ^ 1, (ks + 1) & 1)
            __syncthreads();
        }
    }

    // ---- coalesced epilogue: acc -> LDS bf16 (stride SE) -> full-line stores ----
    __syncthreads();                       // all compute reads of As/Bs done
    u16* eps = (u16*)As;                   // 128*SE = 9216 u16 <= 10240 available
#pragma unroll
    for (int ni = 0; ni < 2; ++ni) {
        int gcl = wn * 32 + ni * 16 + row16;
        float bvv = bias[bn * 64 + gcl];
#pragma unroll
        for (int mi = 0; mi < 4; ++mi)
#pragma unroll
            for (int r = 0; r < 4; ++r)
                eps[(wm * 64 + mi * 16 + quad * 4 + r) * SE + gcl] = f2bf(acc[mi][ni][r] + bvv);
    }
    __syncthreads();
    int mlim = M - bm * 128;
#pragma unroll
    for (int p = 0; p < 4; ++p) {
        int row = p * 32 + (tid >> 3);
        if (row < mlim) {
            int chunk = (tid & 7) * 8;
            uint4 v = *(const uint4*)(eps + row * SE + chunk);
            *(uint4*)(H + (size_t)(bm * 128 + row) * 256 + bn * 64 + chunk) = v;
        }
    }
#undef LOADT
#undef WRITET
}

// ---------------- 2. per-(node,head) attention scores (h bf16) ----------------------
__global__ __launch_bounds__(256) void node_scores(const u16* __restrict__ ha, const u16* __restrict__ hd,
                                                   const float* __restrict__ w_ads, const float* __restrict__ w_add,
                                                   const float* __restrict__ w_dds, const float* __restrict__ w_ddd,
                                                   float* __restrict__ as_ad, float* __restrict__ ad_ad,
                                                   float* __restrict__ as_dd, float* __restrict__ ad_dd, int N) {
    int gid = blockIdx.x * 256 + threadIdx.x;
    int n = gid >> 6;
    if (n >= N) return;
    int lane = gid & 63;
    int f = lane * 4;
    ushort4 av = *(const ushort4*)(ha + (size_t)n * 256 + f);
    ushort4 dv = *(const ushort4*)(hd + (size_t)n * 256 + f);
    float4 w1 = *(const float4*)(w_ads + f);
    float4 w2 = *(const float4*)(w_add + f);
    float4 w3 = *(const float4*)(w_dds + f);
    float4 w4 = *(const float4*)(w_ddd + f);
    float a0 = bf2f(av.x), a1 = bf2f(av.y), a2 = bf2f(av.z), a3 = bf2f(av.w);
    float d0 = bf2f(dv.x), d1 = bf2f(dv.y), d2 = bf2f(dv.z), d3 = bf2f(dv.w);
    float p1 = a0 * w1.x + a1 * w1.y + a2 * w1.z + a3 * w1.w;
    float p2 = d0 * w2.x + d1 * w2.y + d2 * w2.z + d3 * w2.w;
    float p3 = d0 * w3.x + d1 * w3.y + d2 * w3.z + d3 * w3.w;
    float p4 = d0 * w4.x + d1 * w4.y + d2 * w4.z + d3 * w4.w;
#pragma unroll
    for (int off = 16; off >= 1; off >>= 1) {
        p1 += __shfl_down(p1, off, 32);
        p2 += __shfl_down(p2, off, 32);
        p3 += __shfl_down(p3, off, 32);
        p4 += __shfl_down(p4, off, 32);
    }
    if ((lane & 31) == 0) {
        int h = lane >> 5;
        as_ad[n * 2 + h] = p1;
        ad_ad[n * 2 + h] = p2;
        as_dd[n * 2 + h] = p3;
        ad_dd[n * 2 + h] = p4;
    }
}

// ---------------- 3a. degree histogram, both edge sets ------------------------------
__global__ __launch_bounds__(256) void count_edges2(const int* __restrict__ eiA, int* __restrict__ cntA,
                                                    const int* __restrict__ eiB, int* __restrict__ cntB, int E) {
    int idx = blockIdx.x * 256 + threadIdx.x;
    int which = idx >= E;
    int e = idx - (which ? E : 0);
    if (e >= E) return;
    const int* ei = which ? eiB : eiA;
    int* cnt = which ? cntB : cntA;
    atomicAdd(&cnt[ei[E + e]], 1);
}

// ---------------- 3b. exclusive scan (shuffle-based) --------------------------------
__global__ __launch_bounds__(1024) void scan_two(const int* __restrict__ cntA, int* __restrict__ offA,
                                                 const int* __restrict__ cntB, int* __restrict__ offB, int n) {
    const int* cnt = blockIdx.x ? cntB : cntA;
    int* off = blockIdx.x ? offB : offA;
    __shared__ int wsum[16];
    __shared__ int woff[16];
    __shared__ int tot_s;
    __shared__ int carry_s;
    int tid = threadIdx.x, wid = tid >> 6, lane = tid & 63;
    if (tid == 0) carry_s = 0;
    __syncthreads();
    for (int base = 0; base < n; base += 1024) {
        int i = base + tid;
        int v = (i < n) ? cnt[i] : 0;
        int x = v;
#pragma unroll
        for (int d = 1; d < 64; d <<= 1) {
            int t = __shfl_up(x, d, 64);
            if (lane >= d) x += t;
        }
        if (lane == 63) wsum[wid] = x;
        __syncthreads();
        if (wid == 0) {
            int s = (lane < 16) ? wsum[lane] : 0;
#pragma unroll
            for (int d = 1; d < 16; d <<= 1) {
                int t = __shfl_up(s, d, 64);
                if (lane >= d) s += t;
            }
            if (lane < 16) woff[lane] = s - wsum[lane];
            if (lane == 15) tot_s = s;
        }
        __syncthreads();
        int carry = carry_s;
        if (i < n) off[i] = carry + woff[wid] + x - v;
        __syncthreads();
        if (tid == 0) carry_s = carry + tot_s;
    }
    __syncthreads();
    if (tid == 0) off[n] = carry_s;
}

// ---------------- 3c. fill CSR src lists, both edge sets ----------------------------
__global__ __launch_bounds__(256) void fill_csr2(const int* __restrict__ eiA, const int* __restrict__ offA,
                                                 int* __restrict__ curA, int* __restrict__ srcsA,
                                                 const int* __restrict__ eiB, const int* __restrict__ offB,
                                                 int* __restrict__ curB, int* __restrict__ srcsB, int E) {
    int idx = blockIdx.x * 256 + threadIdx.x;
    int which = idx >= E;
    int e = idx - (which ? E : 0);
    if (e >= E) return;
    const int* ei = which ? eiB : eiA;
    const int* off = which ? offB : offA;
    int* cursor = which ? curB : curA;
    int* srcs = which ? srcsB : srcsA;
    int s = ei[e], d = ei[E + e];
    int slot = off[d] + atomicAdd(&cursor[d], 1);
    srcs[slot] = s;
}

// ---------------- 4. gather: one wave per dst node; out bf16 ------------------------
__global__ __launch_bounds__(256) void edge_gather2(const int* __restrict__ offA, const int* __restrict__ srcsA,
                                                    const float* __restrict__ asA, const float* __restrict__ adA,
                                                    const u16* __restrict__ hA, u16* __restrict__ outA,
                                                    const int* __restrict__ offB, const int* __restrict__ srcsB,
                                                    const float* __restrict__ asB, const float* __restrict__ adB,
                                                    const u16* __restrict__ hB, u16* __restrict__ outB, int N) {
    int gid = blockIdx.x * 256 + threadIdx.x;
    int dall = gid >> 6;
    int which = dall >= N;
    int d = dall - (which ? N : 0);
    if (d >= N) return;
    const int* off = which ? offB : offA;
    const int* srcs = which ? srcsB : srcsA;
    const float* a_src = which ? asB : asA;
    const float* a_dst = which ? adB : adA;
    const u16* h = which ? hB : hA;
    u16* out = which ? outB : outA;
    int lane = gid & 63;
    int hh = lane >> 5;
    int f = lane * 4;
    float ad0 = a_dst[d * 2 + hh];
    int beg = off[d], end = off[d + 1];
    float4 acc = {0.f, 0.f, 0.f, 0.f};
    float S = 0.f;
    for (int p = beg; p < end; ++p) {
        int s = srcs[p];
        float v = a_src[s * 2 + hh] + ad0;
        v = v > 0.f ? v : 0.2f * v;           // leaky_relu(0.2)
        float ex = __expf(v);
        S += ex;
        ushort4 xv = *(const ushort4*)(h + (size_t)s * 256 + f);
        acc.x += ex * bf2f(xv.x);
        acc.y += ex * bf2f(xv.y);
        acc.z += ex * bf2f(xv.z);
        acc.w += ex * bf2f(xv.w);
    }
    float inv = 1.f / (S + 1e-16f);
    ushort4 o = {f2bf(acc.x * inv), f2bf(acc.y * inv), f2bf(acc.z * inv), f2bf(acc.w * inv)};
    *(ushort4*)(out + (size_t)d * 256 + f) = o;
}

// ---------------- 5. semantic scores, both metapaths; A is bf16 ---------------------
#define SK 264
__global__ __launch_bounds__(256) void kgemm_score2(const u16* __restrict__ outA,
                                                    const u16* __restrict__ outB,
                                                    const float* __restrict__ kW,
                                                    const float* __restrict__ kb,
                                                    const float* __restrict__ qv,
                                                    float* __restrict__ score) {
    __shared__ u16 Bs[128 * SK];          // 66 KB
    __shared__ float red[4];
    int slot = blockIdx.x >> 8;           // 0..1
    int b = blockIdx.x & 255;
    const u16* outm = slot ? outB : outA;
    int bn = b & 1;
    int bidx = b >> 1;                    // 0..127
    int tid = threadIdx.x;
    int w = tid >> 6, lane = tid & 63;
    int row16 = lane & 15, quad = lane >> 4;

#pragma unroll
    for (int i = 0; i < 16; ++i) {
        int c = tid + 256 * i;
        int r = c >> 5, col8 = (c & 31) * 8;
        const float* src = kW + (size_t)(bn * 128 + r) * 256 + col8;
        *(bf16x8*)(Bs + r * SK + col8) = cvt8(*(const f32x4*)src, *(const f32x4*)(src + 4));
    }
    __syncthreads();

    float kb0 = kb[bn * 128 + w * 32 + row16];
    float qn0 = qv[bn * 128 + w * 32 + row16];
    float kb1 = kb[bn * 128 + w * 32 + 16 + row16];
    float qn1 = qv[bn * 128 + w * 32 + 16 + row16];
    const u16* b0 = Bs + (w * 32 + row16) * SK + quad * 8;
    const u16* b1 = Bs + (w * 32 + 16 + row16) * SK + quad * 8;

    union U { uint4 q; u16 s[8]; bf16x8 v; };
    float p = 0.f;
    for (int mt = bidx; mt < 1250; mt += 128) {
        const u16* arow = outm + (size_t)(mt * 16 + row16) * 256 + quad * 8;
        U a[8];
#pragma unroll
        for (int s8 = 0; s8 < 8; ++s8) a[s8].q = *(const uint4*)(arow + s8 * 32);
        f32x4 acc0 = {0.f,0.f,0.f,0.f}, acc1 = {0.f,0.f,0.f,0.f};
#pragma unroll
        for (int s8 = 0; s8 < 8; ++s8) {
#pragma unroll
            for (int j = 0; j < 8; ++j)       // relu in bf16 domain
                if (a[s8].s[j] & 0x8000u) a[s8].s[j] = 0;
            bf16x8 bf0 = *(const bf16x8*)(b0 + s8 * 32);
            bf16x8 bf1 = *(const bf16x8*)(b1 + s8 * 32);
            acc0 = __builtin_amdgcn_mfma_f32_16x16x32_bf16(a[s8].v, bf0, acc0, 0, 0, 0);
            acc1 = __builtin_amdgcn_mfma_f32_16x16x32_bf16(a[s8].v, bf1, acc1, 0, 0, 0);
        }
#pragma unroll
        for (int r = 0; r < 4; ++r) {
            p += qn0 * fast_tanh(acc0[r] + kb0);
            p += qn1 * fast_tanh(acc1[r] + kb1);
        }
    }
#pragma unroll
    for (int off = 32; off >= 1; off >>= 1) p += __shfl_down(p, off, 64);
    if (lane == 0) red[w] = p;
    __syncthreads();
    if (tid == 0) unsafeAtomicAdd(&score[slot], red[0] + red[1] + red[2] + red[3]);
}

// ---------------- 6. softmax over 2 metapath scores, blend, gather del_idx ----------
__global__ __launch_bounds__(256) void final_combine(const u16* __restrict__ out_ad,
                                                     const u16* __restrict__ out_dd,
                                                     const float* __restrict__ score,
                                                     const int* __restrict__ del_idx,
                                                     float* __restrict__ out) {
    int i = blockIdx.x;
    int f = threadIdx.x;
    int node = del_idx[i];
    float s0 = score[0] * (1.f / 20000.f);
    float s1 = score[1] * (1.f / 20000.f);
    float m = fmaxf(s0, s1);
    float e0 = __expf(s0 - m), e1 = __expf(s1 - m);
    float inv = 1.f / (e0 + e1);
    float a0 = e0 * inv, a1 = e1 * inv;
    float v0 = bf2f(out_ad[(size_t)node * 256 + f]); v0 = v0 > 0.f ? v0 : 0.f;
    float v1 = bf2f(out_dd[(size_t)node * 256 + f]); v1 = v1 > 0.f ? v1 : 0.f;
    out[(size_t)i * 256 + f] = a0 * v0 + a1 * v1;
}

extern "C" void kernel_launch(void* const* d_in, const int* in_sizes, int n_in,
                              void* d_out, int out_size, void* d_ws, size_t ws_size,
                              hipStream_t stream) {
    const float* x_add    = (const float*)d_in[0];
    const float* x_del    = (const float*)d_in[1];
    const float* W_add    = (const float*)d_in[2];
    const float* b_add    = (const float*)d_in[3];
    const float* W_del    = (const float*)d_in[4];
    const float* b_del    = (const float*)d_in[5];
    const float* att_ad_s = (const float*)d_in[6];
    const float* att_ad_d = (const float*)d_in[7];
    const float* att_dd_s = (const float*)d_in[12];
    const float* att_dd_d = (const float*)d_in[13];
    const float* k_W      = (const float*)d_in[14];
    const float* k_b      = (const float*)d_in[15];
    const float* q        = (const float*)d_in[16];
    const int* ei_ad      = (const int*)d_in[17];
    const int* ei_dd      = (const int*)d_in[20];
    const int* del_idx    = (const int*)d_in[21];
    float* out = (float*)d_out;

    const int N = 20000, E = 200000;
    char* ws = (char*)d_ws;
    size_t o = 0;
    // ---- zeroed region ----
    int* cnt_ad = (int*)(ws + o); o += (size_t)N * 4;
    int* cur_ad = (int*)(ws + o); o += (size_t)N * 4;
    int* cnt_dd = (int*)(ws + o); o += (size_t)N * 4;
    int* cur_dd = (int*)(ws + o); o += (size_t)N * 4;
    float* score = (float*)(ws + o); o += 256;
    size_t zero_bytes = o;
    // ---- written-once region ----
    int* off_ad = (int*)(ws + o); o += (size_t)(N + 1) * 4;
    int* off_dd = (int*)(ws + o); o += (size_t)(N + 1) * 4;
    int* srcs_ad = (int*)(ws + o); o += (size_t)E * 4;
    int* srcs_dd = (int*)(ws + o); o += (size_t)E * 4;
    u16* out_ad = (u16*)(ws + o); o += (size_t)N * 256 * 2;
    u16* out_dd = (u16*)(ws + o); o += (size_t)N * 256 * 2;
    u16* ha    = (u16*)(ws + o); o += (size_t)N * 256 * 2;
    u16* hd    = (u16*)(ws + o); o += (size_t)N * 256 * 2;
    float* as_ad = (float*)(ws + o); o += (size_t)N * 2 * 4;
    float* ad_ad = (float*)(ws + o); o += (size_t)N * 2 * 4;
    float* as_dd = (float*)(ws + o); o += (size_t)N * 2 * 4;
    float* ad_dd = (float*)(ws + o); o += (size_t)N * 2 * 4;

    hipMemsetAsync(d_ws, 0, zero_bytes, stream);

    // CSR build (fused pairs)
    count_edges2<<<(2 * E + 255) / 256, 256, 0, stream>>>(ei_ad, cnt_ad, ei_dd, cnt_dd, E);
    scan_two<<<2, 1024, 0, stream>>>(cnt_ad, off_ad, cnt_dd, off_dd, N);
    fill_csr2<<<(2 * E + 255) / 256, 256, 0, stream>>>(ei_ad, off_ad, cur_ad, srcs_ad,
                                                       ei_dd, off_dd, cur_dd, srcs_dd, E);

    // both projections: 2 * (157 m-tiles * 4 n-tiles) = 1256 blocks
    gemm_h2<<<1256, 256, 0, stream>>>(x_add, W_add, b_add, ha,
                                      x_del, W_del, b_del, hd, N);
    node_scores<<<5000, 256, 0, stream>>>(ha, hd, att_ad_s, att_ad_d, att_dd_s, att_dd_d,
                                          as_ad, ad_ad, as_dd, ad_dd, N);

    edge_gather2<<<10000, 256, 0, stream>>>(off_ad, srcs_ad, as_ad, ad_ad, ha, out_ad,
                                            off_dd, srcs_dd, as_dd, ad_dd, hd, out_dd, N);

    kgemm_score2<<<512, 256, 0, stream>>>(out_ad, out_dd, k_W, k_b, q, score);
    final_combine<<<4096, 256, 0, stream>>>(out_ad, out_dd, score, del_idx, out);
}